// Round 1
// baseline (587.076 us; speedup 1.0000x reference)
//
#include <hip/hip_runtime.h>
#include <hip/hip_cooperative_groups.h>
#include <math.h>

namespace cg = cooperative_groups;

#define N 8192
#define NV4 (N / 4)             // float4 columns per row
#define RPB 64                  // rows per block (row-strip)
#define NBY (N / RPB)           // 128 row-strips
#define GRID_X 8                // column chunks: NV4 / THREADS
#define THREADS 256
#define CR 8                    // tile rows register-cached across the grid sync

// ws layout (floats) — every region fully overwritten before read (poison-safe),
// no atomics anywhere:
//   degp  : [NBY][N]      per-row-strip partial column sums      (4 MB)
//   tpart : [NBY][2][N]   per-row-strip partial matvec results   (8 MB)
//   dinvg : [N]           full rsqrt(deg) per column             (32 KB)
//   hpart : [32][2]       per-head-block partial sums of h3
#define DEGP_OFF  0
#define TPART_OFF (NBY * N)
#define DINV_OFF  (TPART_OFF + NBY * 2 * N)
#define HPART_OFF (DINV_OFF + N)

// Fused colsum + weighted matvec. Cooperative: one grid.sync() replaces the
// kernel boundary so (a) CR rows/thread stay live in VGPRs across the sync
// (12.5% of pass-2 traffic never re-read), (b) pass 2 walks rows newest-first
// so the L3-resident copy of DSM (256 MiB == L3 size) is hit LRU-optimally.
__global__ __launch_bounds__(THREADS, 4)
void k_fused(const float* __restrict__ dsm, float* __restrict__ degp,
             const float* __restrict__ x, float* __restrict__ dinvg,
             float* __restrict__ tpart) {
    __shared__ float sred[4 * RPB];
    __shared__ float sg0[RPB];
    __shared__ float sg1[RPB];

    int chunk = (blockIdx.x + blockIdx.y) & (GRID_X - 1);   // column-phase swizzle
    int c4 = chunk * THREADS + threadIdx.x;
    int r0 = blockIdx.y * RPB;
    const float4* p = (const float4*)dsm + (size_t)r0 * NV4 + c4;

    // ---- Pass 1: per-strip partial column sums; cache first CR rows in regs.
    float4 cache[CR];
    float4 acc = {0.f, 0.f, 0.f, 0.f};
#pragma unroll
    for (int i = 0; i < CR; ++i) {
        float4 v = p[(size_t)i * NV4];
        cache[i] = v;
        acc.x += v.x; acc.y += v.y; acc.z += v.z; acc.w += v.w;
    }
#pragma unroll 8
    for (int i = CR; i < RPB; ++i) {
        float4 v = p[(size_t)i * NV4];
        acc.x += v.x; acc.y += v.y; acc.z += v.z; acc.w += v.w;
    }
    ((float4*)(degp + (size_t)blockIdx.y * N))[c4] = acc;

    cg::this_grid().sync();

    // ---- Phase A: full deg for our 64 rows -> dinv -> gather weights in LDS.
    {
        int rl = threadIdx.x & 63;          // row within strip
        int q  = threadIdx.x >> 6;          // quarter: 32 strips each
        const float* dp = degp + r0 + rl;
        float s = 0.f;
#pragma unroll 8
        for (int j = 0; j < 32; ++j) s += dp[(size_t)(q * 32 + j) * N];
        sred[q * RPB + rl] = s;
    }
    __syncthreads();
    if (threadIdx.x < RPB) {
        int r = threadIdx.x;
        float d = sred[r] + sred[RPB + r] + sred[2 * RPB + r] + sred[3 * RPB + r];
        float di = d > 0.f ? rsqrtf(d) : 0.f;
        sg0[r] = di * x[r0 + r];
        sg1[r] = di * x[N + r0 + r];
        if (blockIdx.x == 0) dinvg[r0 + r] = di;   // once per row, for k_head
    }
    __syncthreads();

    // ---- Pass 2: weighted partial matvec. Newest rows first (L3 LRU), then
    // the register-cached rows (never touch memory).
    float4 a0 = {0.f, 0.f, 0.f, 0.f};
    float4 a1 = {0.f, 0.f, 0.f, 0.f};
#pragma unroll 8
    for (int i = RPB - 1; i >= CR; --i) {
        float4 v = p[(size_t)i * NV4];
        float g0 = sg0[i], g1 = sg1[i];
        a0.x += v.x * g0; a0.y += v.y * g0; a0.z += v.z * g0; a0.w += v.w * g0;
        a1.x += v.x * g1; a1.y += v.y * g1; a1.z += v.z * g1; a1.w += v.w * g1;
    }
#pragma unroll
    for (int i = 0; i < CR; ++i) {
        float4 v = cache[i];
        float g0 = sg0[i], g1 = sg1[i];
        a0.x += v.x * g0; a0.y += v.y * g0; a0.z += v.z * g0; a0.w += v.w * g0;
        a1.x += v.x * g1; a1.y += v.y * g1; a1.z += v.z * g1; a1.w += v.w * g1;
    }
    ((float4*)(tpart + ((size_t)blockIdx.y * 2 + 0) * N))[c4] = a0;
    ((float4*)(tpart + ((size_t)blockIdx.y * 2 + 1) * N))[c4] = a1;
}

__global__ void k_head(const float* __restrict__ dinvg, const float* __restrict__ tpart,
                       const float* __restrict__ w1, const float* __restrict__ b1,
                       const float* __restrict__ lw1, const float* __restrict__ lb1,
                       const float* __restrict__ lw2, const float* __restrict__ lb2,
                       float* __restrict__ hpart, float* __restrict__ out) {
    __shared__ float swred[8];   // 4 waves x 2 batches
    int c = blockIdx.x * THREADS + threadIdx.x;

    float t0 = 0.f, t1 = 0.f;
#pragma unroll 8
    for (int by = 0; by < NBY; ++by) {
        t0 += tpart[((size_t)by * 2 + 0) * N + c];
        t1 += tpart[((size_t)by * 2 + 1) * N + c];
    }
    float di = dinvg[c];

    float W1 = w1[0], B1 = b1[0];
    float LW1 = lw1[0], LB1 = lb1[0];
    float LW2 = lw2[0], LB2 = lb2[0];
    float h0 = fmaxf(W1 * di * t0 + B1, 0.f);
    h0 = fmaxf(h0 * LW1 + LB1, 0.f);
    h0 = fmaxf(h0 * LW2 + LB2, 0.f);
    float h1 = fmaxf(W1 * di * t1 + B1, 0.f);
    h1 = fmaxf(h1 * LW1 + LB1, 0.f);
    h1 = fmaxf(h1 * LW2 + LB2, 0.f);

    // softmax over singleton last axis == 1.0 exactly
    out[c] = 1.0f;
    out[N + c] = 1.0f;

    // block reduction: wave shuffle then LDS across 4 waves
    float v0 = h0, v1 = h1;
    for (int off = 32; off > 0; off >>= 1) {
        v0 += __shfl_down(v0, off);
        v1 += __shfl_down(v1, off);
    }
    int wave = threadIdx.x >> 6;
    if ((threadIdx.x & 63) == 0) { swred[wave] = v0; swred[4 + wave] = v1; }
    __syncthreads();
    if (threadIdx.x == 0) {
        hpart[blockIdx.x * 2 + 0] = swred[0] + swred[1] + swred[2] + swred[3];
        hpart[blockIdx.x * 2 + 1] = swred[4] + swred[5] + swred[6] + swred[7];
    }
}

__global__ void k_out(const float* __restrict__ hpart,
                      const float* __restrict__ w2, const float* __restrict__ b2,
                      const float* __restrict__ w3, const float* __restrict__ b3,
                      const float* __restrict__ wv, const float* __restrict__ bv,
                      float* __restrict__ out) {
    int tid = threadIdx.x;
    float s0 = tid < 32 ? hpart[tid * 2 + 0] : 0.f;
    float s1 = tid < 32 ? hpart[tid * 2 + 1] : 0.f;
    for (int off = 16; off > 0; off >>= 1) {
        s0 += __shfl_down(s0, off);
        s1 += __shfl_down(s1, off);
    }
    if (tid == 0) {
        float m0 = s0 * (1.0f / (float)N);
        float m1 = s1 * (1.0f / (float)N);
        float a = fmaxf(m0 * w2[0] + b2[0], 0.f);
        a = fmaxf(a * w3[0] + b3[0], 0.f);
        float b = fmaxf(m1 * w2[0] + b2[0], 0.f);
        b = fmaxf(b * w3[0] + b3[0], 0.f);
        float vmax = fmaxf(a, b);
        out[2 * N] = vmax * wv[0] + bv[0];
    }
}

extern "C" void kernel_launch(void* const* d_in, const int* in_sizes, int n_in,
                              void* d_out, int out_size, void* d_ws, size_t ws_size,
                              hipStream_t stream) {
    const float* x   = (const float*)d_in[0];
    const float* dsm = (const float*)d_in[1];
    const float* w1  = (const float*)d_in[2];
    const float* b1  = (const float*)d_in[3];
    const float* lw1 = (const float*)d_in[4];
    const float* lb1 = (const float*)d_in[5];
    const float* lw2 = (const float*)d_in[6];
    const float* lb2 = (const float*)d_in[7];
    const float* w2  = (const float*)d_in[8];
    const float* b2  = (const float*)d_in[9];
    const float* w3  = (const float*)d_in[10];
    const float* b3  = (const float*)d_in[11];
    // d_in[12..13] = wa, ba unused: softmax over a singleton axis == 1.0
    const float* wv  = (const float*)d_in[14];
    const float* bv  = (const float*)d_in[15];

    float* ws    = (float*)d_ws;
    float* degp  = ws + DEGP_OFF;
    float* tpart = ws + TPART_OFF;
    float* dinvg = ws + DINV_OFF;
    float* hpart = ws + HPART_OFF;

    void* kargs[] = {(void*)&dsm, (void*)&degp, (void*)&x, (void*)&dinvg, (void*)&tpart};
    hipLaunchCooperativeKernel((const void*)k_fused, dim3(GRID_X, NBY), dim3(THREADS),
                               kargs, 0, stream);
    k_head<<<N / THREADS, THREADS, 0, stream>>>(dinvg, tpart, w1, b1, lw1, lb1,
                                                lw2, lb2, hpart, (float*)d_out);
    k_out<<<1, 64, 0, stream>>>(hpart, w2, b2, w3, b3, wv, bv, (float*)d_out);
}

// Round 2
// 470.842 us; speedup vs baseline: 1.2469x; 1.2469x over previous
//
#include <hip/hip_runtime.h>
#include <math.h>

#define N 8192
#define NV4 (N / 4)             // float4 columns per row
#define RPB 32                  // rows per block (row-strip)
#define NBY (N / RPB)           // 256 row-strips
#define GRID_X 8                // column chunks: NV4 / THREADS
#define THREADS 256

typedef float f4 __attribute__((ext_vector_type(4)));

// ws layout (floats) — every region fully overwritten before read (poison-safe),
// no atomics anywhere:
//   degp  : [NBY][N]      per-row-strip partial column sums      (8 MB)
//   tpart : [NBY][2][N]   per-row-strip partial matvec results   (16 MB)
//   dinvg : [N]           rsqrt(deg)
//   g0,g1 : [N]           dinv[r] * x[b][r] per batch
//   hpart : [32][2]       per-head-block partial sums of h3
#define DEGP_OFF  0
#define TPART_OFF (NBY * N)
#define DINV_OFF  (TPART_OFF + NBY * 2 * N)
#define G0_OFF    (DINV_OFF + N)
#define G1_OFF    (G0_OFF + N)
#define HPART_OFF (G1_OFF + N)

// Pass 1: per-strip partial column sums. NT store: degp is single-consumer
// (k_dinv) — don't evict L3-resident DSM with it.
__global__ void k_colsum(const float* __restrict__ dsm, float* __restrict__ degp) {
    int chunk = (blockIdx.x + blockIdx.y) & (GRID_X - 1);   // column-phase swizzle
    int c4 = chunk * THREADS + threadIdx.x;
    int r0 = blockIdx.y * RPB;
    const f4* p = (const f4*)dsm + (size_t)r0 * NV4 + c4;
    f4 acc = 0.f;
#pragma unroll 8
    for (int i = 0; i < RPB; ++i) acc += p[(size_t)i * NV4];
    __builtin_nontemporal_store(acc, (f4*)(degp + (size_t)blockIdx.y * N) + c4);
}

// Tiny: full deg reduction + dinv + pre-scaled per-row gather weights.
// 128 blocks x 256 threads; each block owns 64 columns, 4-way strip split.
__global__ void k_dinv(const float* __restrict__ degp, const float* __restrict__ x,
                       float* __restrict__ dinvg, float* __restrict__ g0,
                       float* __restrict__ g1) {
    __shared__ float sred[4][64];
    int c0 = blockIdx.x * 64;
    int cl = threadIdx.x & 63;
    int q  = threadIdx.x >> 6;
    const float* dp = degp + c0 + cl;
    float s = 0.f;
#pragma unroll 8
    for (int j = 0; j < NBY / 4; ++j) s += dp[(size_t)(q * (NBY / 4) + j) * N];
    sred[q][cl] = s;
    __syncthreads();
    if (threadIdx.x < 64) {
        int c = c0 + threadIdx.x;
        float d = sred[0][threadIdx.x] + sred[1][threadIdx.x] +
                  sred[2][threadIdx.x] + sred[3][threadIdx.x];
        float di = d > 0.f ? rsqrtf(d) : 0.f;
        dinvg[c] = di;
        g0[c] = di * x[c];
        g1[c] = di * x[N + c];
    }
}

// Pass 2: weighted partial matvec over a 32-row strip. Phase A is now just a
// 32-float LDS fill; DSM reads should be L3-hits. NT store for tpart.
__global__ void k_matvec(const float* __restrict__ dsm, const float* __restrict__ g0,
                         const float* __restrict__ g1, float* __restrict__ tpart) {
    __shared__ float sg0[RPB];
    __shared__ float sg1[RPB];
    int r0 = blockIdx.y * RPB;
    if (threadIdx.x < RPB) {
        sg0[threadIdx.x] = g0[r0 + threadIdx.x];
        sg1[threadIdx.x] = g1[r0 + threadIdx.x];
    }
    __syncthreads();
    int chunk = (blockIdx.x + blockIdx.y) & (GRID_X - 1);
    int c4 = chunk * THREADS + threadIdx.x;
    const f4* p = (const f4*)dsm + (size_t)r0 * NV4 + c4;
    f4 a0 = 0.f, a1 = 0.f;
#pragma unroll 8
    for (int i = 0; i < RPB; ++i) {
        f4 v = p[(size_t)i * NV4];
        a0 += v * sg0[i];
        a1 += v * sg1[i];
    }
    __builtin_nontemporal_store(a0, (f4*)(tpart + ((size_t)blockIdx.y * 2 + 0) * N) + c4);
    __builtin_nontemporal_store(a1, (f4*)(tpart + ((size_t)blockIdx.y * 2 + 1) * N) + c4);
}

__global__ void k_head(const float* __restrict__ dinvg, const float* __restrict__ tpart,
                       const float* __restrict__ w1, const float* __restrict__ b1,
                       const float* __restrict__ lw1, const float* __restrict__ lb1,
                       const float* __restrict__ lw2, const float* __restrict__ lb2,
                       float* __restrict__ hpart, float* __restrict__ out) {
    __shared__ float swred[8];   // 4 waves x 2 batches
    int c = blockIdx.x * THREADS + threadIdx.x;

    float t0 = 0.f, t1 = 0.f;
#pragma unroll 8
    for (int by = 0; by < NBY; ++by) {
        t0 += tpart[((size_t)by * 2 + 0) * N + c];
        t1 += tpart[((size_t)by * 2 + 1) * N + c];
    }
    float di = dinvg[c];

    float W1 = w1[0], B1 = b1[0];
    float LW1 = lw1[0], LB1 = lb1[0];
    float LW2 = lw2[0], LB2 = lb2[0];
    float h0 = fmaxf(W1 * di * t0 + B1, 0.f);
    h0 = fmaxf(h0 * LW1 + LB1, 0.f);
    h0 = fmaxf(h0 * LW2 + LB2, 0.f);
    float h1 = fmaxf(W1 * di * t1 + B1, 0.f);
    h1 = fmaxf(h1 * LW1 + LB1, 0.f);
    h1 = fmaxf(h1 * LW2 + LB2, 0.f);

    // softmax over singleton last axis == 1.0 exactly
    out[c] = 1.0f;
    out[N + c] = 1.0f;

    // block reduction: wave shuffle then LDS across 4 waves
    float v0 = h0, v1 = h1;
    for (int off = 32; off > 0; off >>= 1) {
        v0 += __shfl_down(v0, off);
        v1 += __shfl_down(v1, off);
    }
    int wave = threadIdx.x >> 6;
    if ((threadIdx.x & 63) == 0) { swred[wave] = v0; swred[4 + wave] = v1; }
    __syncthreads();
    if (threadIdx.x == 0) {
        hpart[blockIdx.x * 2 + 0] = swred[0] + swred[1] + swred[2] + swred[3];
        hpart[blockIdx.x * 2 + 1] = swred[4] + swred[5] + swred[6] + swred[7];
    }
}

__global__ void k_out(const float* __restrict__ hpart,
                      const float* __restrict__ w2, const float* __restrict__ b2,
                      const float* __restrict__ w3, const float* __restrict__ b3,
                      const float* __restrict__ wv, const float* __restrict__ bv,
                      float* __restrict__ out) {
    int tid = threadIdx.x;
    float s0 = tid < 32 ? hpart[tid * 2 + 0] : 0.f;
    float s1 = tid < 32 ? hpart[tid * 2 + 1] : 0.f;
    for (int off = 16; off > 0; off >>= 1) {
        s0 += __shfl_down(s0, off);
        s1 += __shfl_down(s1, off);
    }
    if (tid == 0) {
        float m0 = s0 * (1.0f / (float)N);
        float m1 = s1 * (1.0f / (float)N);
        float a = fmaxf(m0 * w2[0] + b2[0], 0.f);
        a = fmaxf(a * w3[0] + b3[0], 0.f);
        float b = fmaxf(m1 * w2[0] + b2[0], 0.f);
        b = fmaxf(b * w3[0] + b3[0], 0.f);
        float vmax = fmaxf(a, b);
        out[2 * N] = vmax * wv[0] + bv[0];
    }
}

extern "C" void kernel_launch(void* const* d_in, const int* in_sizes, int n_in,
                              void* d_out, int out_size, void* d_ws, size_t ws_size,
                              hipStream_t stream) {
    const float* x   = (const float*)d_in[0];
    const float* dsm = (const float*)d_in[1];
    const float* w1  = (const float*)d_in[2];
    const float* b1  = (const float*)d_in[3];
    const float* lw1 = (const float*)d_in[4];
    const float* lb1 = (const float*)d_in[5];
    const float* lw2 = (const float*)d_in[6];
    const float* lb2 = (const float*)d_in[7];
    const float* w2  = (const float*)d_in[8];
    const float* b2  = (const float*)d_in[9];
    const float* w3  = (const float*)d_in[10];
    const float* b3  = (const float*)d_in[11];
    // d_in[12..13] = wa, ba unused: softmax over a singleton axis == 1.0
    const float* wv  = (const float*)d_in[14];
    const float* bv  = (const float*)d_in[15];

    float* ws    = (float*)d_ws;
    float* degp  = ws + DEGP_OFF;
    float* tpart = ws + TPART_OFF;
    float* dinvg = ws + DINV_OFF;
    float* g0    = ws + G0_OFF;
    float* g1    = ws + G1_OFF;
    float* hpart = ws + HPART_OFF;

    dim3 big(GRID_X, NBY);   // (8, 256) = 2048 blocks
    k_colsum<<<big, THREADS, 0, stream>>>(dsm, degp);
    k_dinv<<<N / 64, THREADS, 0, stream>>>(degp, x, dinvg, g0, g1);
    k_matvec<<<big, THREADS, 0, stream>>>(dsm, g0, g1, tpart);
    k_head<<<N / THREADS, THREADS, 0, stream>>>(dinvg, tpart, w1, b1, lw1, lb1,
                                                lw2, lb2, hpart, (float*)d_out);
    k_out<<<1, 64, 0, stream>>>(hpart, w2, b2, w3, b3, wv, bv, (float*)d_out);
}

// Round 3
// 433.057 us; speedup vs baseline: 1.3557x; 1.0872x over previous
//
#include <hip/hip_runtime.h>
#include <math.h>

#define N 8192
#define NV4 (N / 4)             // float4 columns per row
#define RPB 64                  // rows per block (row-strip)
#define NBY (N / RPB)           // 128 row-strips
#define GRID_X 8                // column chunks: NV4 / THREADS
#define THREADS 256

typedef float f4 __attribute__((ext_vector_type(4)));

// ws layout (floats) — every region fully overwritten before read (poison-safe),
// no atomics anywhere. All partials use normal (cached) stores so consumers
// read from L2/L3, not HBM (NT stores regressed round 2 by ~30 µs).
//   degp  : [NBY][N]      per-row-strip partial column sums      (4 MB)
//   tpart : [NBY][2][N]   per-row-strip partial matvec results   (8 MB)
//   dinvg : [N]           rsqrt(deg)
//   g0,g1 : [N]           dinv[r] * x[b][r] per batch
//   hpart : [2][32]       per-(batch, head-block) partial sums of h3
#define DEGP_OFF  0
#define TPART_OFF (NBY * N)
#define DINV_OFF  (TPART_OFF + NBY * 2 * N)
#define G0_OFF    (DINV_OFF + N)
#define G1_OFF    (G0_OFF + N)
#define HPART_OFF (G1_OFF + N)

// Pass 1: per-strip partial column sums (DSM streamed HBM->L3, read once).
__global__ void k_colsum(const float* __restrict__ dsm, float* __restrict__ degp) {
    int chunk = (blockIdx.x + blockIdx.y) & (GRID_X - 1);   // column-phase swizzle
    int c4 = chunk * THREADS + threadIdx.x;
    int r0 = blockIdx.y * RPB;
    const f4* p = (const f4*)dsm + (size_t)r0 * NV4 + c4;
    f4 acc = 0.f;
#pragma unroll 8
    for (int i = 0; i < RPB; ++i) acc += p[(size_t)i * NV4];
    ((f4*)(degp + (size_t)blockIdx.y * N))[c4] = acc;
}

// Tiny: full deg reduction + dinv + pre-scaled per-row gather weights.
// 256 blocks x 256 threads; block owns 32 columns, 8-way strip split.
// degp is L3-resident (4 MB, just written).
__global__ void k_dinv(const float* __restrict__ degp, const float* __restrict__ x,
                       float* __restrict__ dinvg, float* __restrict__ g0,
                       float* __restrict__ g1) {
    __shared__ float sred[8][32];
    int c0 = blockIdx.x * 32;
    int cl = threadIdx.x & 31;
    int q  = threadIdx.x >> 5;
    const float* dp = degp + c0 + cl;
    float s = 0.f;
#pragma unroll 8
    for (int j = 0; j < NBY / 8; ++j) s += dp[(size_t)(q * (NBY / 8) + j) * N];
    sred[q][cl] = s;
    __syncthreads();
    if (threadIdx.x < 32) {
        int c = c0 + threadIdx.x;
        float d = 0.f;
#pragma unroll
        for (int q2 = 0; q2 < 8; ++q2) d += sred[q2][threadIdx.x];
        float di = d > 0.f ? rsqrtf(d) : 0.f;
        dinvg[c] = di;
        g0[c] = di * x[c];
        g1[c] = di * x[N + c];
    }
}

// Pass 2: weighted partial matvec over a 64-row strip. Phase A is one 64-float
// LDS fill; DSM reads should be L3-hits (256 MiB == L3 size, read in pass 1).
__global__ void k_matvec(const float* __restrict__ dsm, const float* __restrict__ g0,
                         const float* __restrict__ g1, float* __restrict__ tpart) {
    __shared__ float sg0[RPB];
    __shared__ float sg1[RPB];
    int r0 = blockIdx.y * RPB;
    if (threadIdx.x < RPB) {
        sg0[threadIdx.x] = g0[r0 + threadIdx.x];
        sg1[threadIdx.x] = g1[r0 + threadIdx.x];
    }
    __syncthreads();
    int chunk = (blockIdx.x + blockIdx.y) & (GRID_X - 1);
    int c4 = chunk * THREADS + threadIdx.x;
    const f4* p = (const f4*)dsm + (size_t)r0 * NV4 + c4;
    f4 a0 = 0.f, a1 = 0.f;
#pragma unroll 8
    for (int i = 0; i < RPB; ++i) {
        f4 v = p[(size_t)i * NV4];
        a0 += v * sg0[i];
        a1 += v * sg1[i];
    }
    ((f4*)(tpart + ((size_t)blockIdx.y * 2 + 0) * N))[c4] = a0;
    ((f4*)(tpart + ((size_t)blockIdx.y * 2 + 1) * N))[c4] = a1;
}

// Head: grid (32, 2) — blockIdx.y = batch. Each thread reduces one column's
// strip partials (L3-resident tpart), applies the scalar MLP chain, and the
// block reduces h3 for the final mean.
__global__ void k_head(const float* __restrict__ dinvg, const float* __restrict__ tpart,
                       const float* __restrict__ w1, const float* __restrict__ b1,
                       const float* __restrict__ lw1, const float* __restrict__ lb1,
                       const float* __restrict__ lw2, const float* __restrict__ lb2,
                       float* __restrict__ hpart, float* __restrict__ out) {
    __shared__ float swred[4];
    int c = blockIdx.x * THREADS + threadIdx.x;
    int b = blockIdx.y;

    const float* tp = tpart + (size_t)b * N + c;
    float t = 0.f;
#pragma unroll 8
    for (int by = 0; by < NBY; ++by) t += tp[(size_t)by * 2 * N];
    float di = dinvg[c];

    float h = fmaxf(w1[0] * di * t + b1[0], 0.f);
    h = fmaxf(h * lw1[0] + lb1[0], 0.f);
    h = fmaxf(h * lw2[0] + lb2[0], 0.f);

    // softmax over singleton last axis == 1.0 exactly
    out[(size_t)b * N + c] = 1.0f;

    // block reduction: wave shuffle then LDS across 4 waves
    float v = h;
    for (int off = 32; off > 0; off >>= 1) v += __shfl_down(v, off);
    int wave = threadIdx.x >> 6;
    if ((threadIdx.x & 63) == 0) swred[wave] = v;
    __syncthreads();
    if (threadIdx.x == 0)
        hpart[b * 32 + blockIdx.x] = swred[0] + swred[1] + swred[2] + swred[3];
}

__global__ void k_out(const float* __restrict__ hpart,
                      const float* __restrict__ w2, const float* __restrict__ b2,
                      const float* __restrict__ w3, const float* __restrict__ b3,
                      const float* __restrict__ wv, const float* __restrict__ bv,
                      float* __restrict__ out) {
    int tid = threadIdx.x;
    float s0 = tid < 32 ? hpart[tid] : 0.f;
    float s1 = tid < 32 ? hpart[32 + tid] : 0.f;
    for (int off = 16; off > 0; off >>= 1) {
        s0 += __shfl_down(s0, off);
        s1 += __shfl_down(s1, off);
    }
    if (tid == 0) {
        float m0 = s0 * (1.0f / (float)N);
        float m1 = s1 * (1.0f / (float)N);
        float a = fmaxf(m0 * w2[0] + b2[0], 0.f);
        a = fmaxf(a * w3[0] + b3[0], 0.f);
        float b = fmaxf(m1 * w2[0] + b2[0], 0.f);
        b = fmaxf(b * w3[0] + b3[0], 0.f);
        float vmax = fmaxf(a, b);
        out[2 * N] = vmax * wv[0] + bv[0];
    }
}

extern "C" void kernel_launch(void* const* d_in, const int* in_sizes, int n_in,
                              void* d_out, int out_size, void* d_ws, size_t ws_size,
                              hipStream_t stream) {
    const float* x   = (const float*)d_in[0];
    const float* dsm = (const float*)d_in[1];
    const float* w1  = (const float*)d_in[2];
    const float* b1  = (const float*)d_in[3];
    const float* lw1 = (const float*)d_in[4];
    const float* lb1 = (const float*)d_in[5];
    const float* lw2 = (const float*)d_in[6];
    const float* lb2 = (const float*)d_in[7];
    const float* w2  = (const float*)d_in[8];
    const float* b2  = (const float*)d_in[9];
    const float* w3  = (const float*)d_in[10];
    const float* b3  = (const float*)d_in[11];
    // d_in[12..13] = wa, ba unused: softmax over a singleton axis == 1.0
    const float* wv  = (const float*)d_in[14];
    const float* bv  = (const float*)d_in[15];

    float* ws    = (float*)d_ws;
    float* degp  = ws + DEGP_OFF;
    float* tpart = ws + TPART_OFF;
    float* dinvg = ws + DINV_OFF;
    float* g0    = ws + G0_OFF;
    float* g1    = ws + G1_OFF;
    float* hpart = ws + HPART_OFF;

    dim3 big(GRID_X, NBY);   // (8, 128) = 1024 blocks
    k_colsum<<<big, THREADS, 0, stream>>>(dsm, degp);
    k_dinv<<<N / 32, THREADS, 0, stream>>>(degp, x, dinvg, g0, g1);
    k_matvec<<<big, THREADS, 0, stream>>>(dsm, g0, g1, tpart);
    k_head<<<dim3(N / THREADS, 2), THREADS, 0, stream>>>(dinvg, tpart, w1, b1,
                                                         lw1, lb1, lw2, lb2,
                                                         hpart, (float*)d_out);
    k_out<<<1, 64, 0, stream>>>(hpart, w2, b2, w3, b3, wv, bv, (float*)d_out);
}